// Round 1
// baseline (338.268 us; speedup 1.0000x reference)
//
#include <hip/hip_runtime.h>
#include <hip/hip_bf16.h>
#include <math.h>

// Problem constants (fixed shape)
#define T_ 1024
#define H_ 1024
#define I_ 2048
#define E_ 8
#define TOPK_ 2
#define NSLOT 2048   // T_*TOPK_ compacted (token,k) slots, always exactly 2048

// GEMM tiling
#define BM 128
#define BN 64
#define BK 32
#define CHUNKS_PER_E (NSLOT / BM)   // 16: worst-case capacity per expert

typedef __attribute__((ext_vector_type(8))) short bf16x8;
typedef __attribute__((ext_vector_type(4))) short short4v;
typedef __attribute__((ext_vector_type(4))) float f32x4;

__device__ __forceinline__ short f2bf(float f) {
  union { float f; unsigned u; } v; v.f = f;
  unsigned r = v.u + 0x7FFFu + ((v.u >> 16) & 1u);   // round-to-nearest-even
  return (short)(r >> 16);
}

// ---------------------------------------------------------------------------
// Kernel 1: build compacted per-expert slot lists + normalized combine weights
// ---------------------------------------------------------------------------
__global__ __launch_bounds__(1024) void k_build(
    const float* __restrict__ aff, const int* __restrict__ eidx,
    int* __restrict__ offs, int* __restrict__ slot_tok, float* __restrict__ slot_w) {
  __shared__ int cnt[E_];
  __shared__ int soff[E_ + 1];
  int t = threadIdx.x;
  if (t < E_) cnt[t] = 0;
  __syncthreads();
  int e0 = eidx[t * 2 + 0];
  int e1 = eidx[t * 2 + 1];
  float a0 = aff[t * E_ + e0];
  float a1 = aff[t * E_ + e1];
  float inv = 1.0f / (a0 + a1);
  int r0 = atomicAdd(&cnt[e0], 1);
  int r1 = atomicAdd(&cnt[e1], 1);
  __syncthreads();
  if (t == 0) {
    int s = 0;
    for (int e = 0; e < E_; ++e) { soff[e] = s; s += cnt[e]; }
    soff[E_] = s;
  }
  __syncthreads();
  if (t <= E_) offs[t] = soff[t];
  int s0 = soff[e0] + r0;
  int s1 = soff[e1] + r1;
  slot_tok[s0] = t; slot_w[s0] = a0 * inv;
  slot_tok[s1] = t; slot_w[s1] = a1 * inv;
}

// ---------------------------------------------------------------------------
// Kernel 2: grouped GEMM  act[slot, i] = silu(X@Wg) * (X@Wu)  (bf16 out)
// ---------------------------------------------------------------------------
__global__ __launch_bounds__(256) void k_gemm1(
    const float* __restrict__ hs, const float* __restrict__ wg,
    const float* __restrict__ wu, const int* __restrict__ offs,
    const int* __restrict__ slot_tok, short* __restrict__ act) {
  int e = blockIdx.y >> 4;
  int chunk = blockIdx.y & (CHUNKS_PER_E - 1);
  int lo = offs[e], hi = offs[e + 1];
  int row0 = lo + chunk * BM;
  if (row0 >= hi) return;
  int rows = min(BM, hi - row0);
  int i0 = blockIdx.x * BN;

  __shared__ short sA[BM * BK];      // [row][k]  row-major
  __shared__ short sBg[BN * BK];     // [i][k]    transposed (k contiguous)
  __shared__ short sBu[BN * BK];

  int tid = threadIdx.x;
  int lane = tid & 63;
  int wid = tid >> 6;
  int wm = wid >> 1, wn = wid & 1;   // 2x2 wave grid, each wave 64x32
  int lr = lane & 15;
  int lk = (lane >> 4) * 8;

  const float* wgE = wg + (size_t)e * H_ * I_;
  const float* wuE = wu + (size_t)e * H_ * I_;

  f32x4 accg[4][2], accu[4][2];
#pragma unroll
  for (int mr = 0; mr < 4; ++mr)
#pragma unroll
    for (int nr = 0; nr < 2; ++nr) {
      accg[mr][nr] = (f32x4){0.f, 0.f, 0.f, 0.f};
      accu[mr][nr] = (f32x4){0.f, 0.f, 0.f, 0.f};
    }

  // token ids for this thread's A-staging rows are k-invariant: hoist
  int atok[4];
#pragma unroll
  for (int it = 0; it < 4; ++it) {
    int idx = tid + it * 256;
    int r = idx >> 3;
    atok[it] = slot_tok[(r < rows) ? (row0 + r) : row0];
  }

  for (int k0 = 0; k0 < H_; k0 += BK) {
    __syncthreads();
    // stage A: 128x32 f32 -> bf16 (gathered token rows)
#pragma unroll
    for (int it = 0; it < 4; ++it) {
      int idx = tid + it * 256;           // 0..1023
      int r = idx >> 3;
      int c4 = (idx & 7) * 4;
      const float4 v = *(const float4*)&hs[(size_t)atok[it] * H_ + k0 + c4];
      short4v s;
      s.x = f2bf(v.x); s.y = f2bf(v.y); s.z = f2bf(v.z); s.w = f2bf(v.w);
      *(short4v*)&sA[r * BK + c4] = s;
    }
    // stage Bg/Bu: 32x64 f32 -> bf16, transposed into [i][k]
#pragma unroll
    for (int it = 0; it < 2; ++it) {
      int idx = tid + it * 256;           // 0..511
      int hr = idx >> 4;
      int i4 = (idx & 15) * 4;
      const float4 vg = *(const float4*)&wgE[(size_t)(k0 + hr) * I_ + i0 + i4];
      const float4 vu = *(const float4*)&wuE[(size_t)(k0 + hr) * I_ + i0 + i4];
      sBg[(i4 + 0) * BK + hr] = f2bf(vg.x);
      sBg[(i4 + 1) * BK + hr] = f2bf(vg.y);
      sBg[(i4 + 2) * BK + hr] = f2bf(vg.z);
      sBg[(i4 + 3) * BK + hr] = f2bf(vg.w);
      sBu[(i4 + 0) * BK + hr] = f2bf(vu.x);
      sBu[(i4 + 1) * BK + hr] = f2bf(vu.y);
      sBu[(i4 + 2) * BK + hr] = f2bf(vu.z);
      sBu[(i4 + 3) * BK + hr] = f2bf(vu.w);
    }
    __syncthreads();

    bf16x8 a[4], bg[2], bu[2];
#pragma unroll
    for (int mr = 0; mr < 4; ++mr)
      a[mr] = *(const bf16x8*)&sA[(wm * 64 + mr * 16 + lr) * BK + lk];
#pragma unroll
    for (int nr = 0; nr < 2; ++nr) {
      int col = wn * 32 + nr * 16 + lr;
      bg[nr] = *(const bf16x8*)&sBg[col * BK + lk];
      bu[nr] = *(const bf16x8*)&sBu[col * BK + lk];
    }
#pragma unroll
    for (int mr = 0; mr < 4; ++mr)
#pragma unroll
      for (int nr = 0; nr < 2; ++nr) {
        accg[mr][nr] = __builtin_amdgcn_mfma_f32_16x16x32_bf16(a[mr], bg[nr], accg[mr][nr], 0, 0, 0);
        accu[mr][nr] = __builtin_amdgcn_mfma_f32_16x16x32_bf16(a[mr], bu[nr], accu[mr][nr], 0, 0, 0);
      }
  }

  // epilogue: silu(g)*u -> bf16 act
#pragma unroll
  for (int mr = 0; mr < 4; ++mr) {
#pragma unroll
    for (int r = 0; r < 4; ++r) {
      int m = wm * 64 + mr * 16 + (lane >> 4) * 4 + r;
      if (m < rows) {
#pragma unroll
        for (int nr = 0; nr < 2; ++nr) {
          float g = accg[mr][nr][r];
          float u = accu[mr][nr][r];
          float sg = 1.0f / (1.0f + __expf(-g));
          int icol = i0 + wn * 32 + nr * 16 + lr;
          act[(size_t)(row0 + m) * I_ + icol] = f2bf(g * sg * u);
        }
      }
    }
  }
}

// ---------------------------------------------------------------------------
// Kernel 3: grouped GEMM  out[tok, h] += combine_w * (act[slot,:] @ Wd[e])
// ---------------------------------------------------------------------------
__global__ __launch_bounds__(256) void k_gemm2(
    const short* __restrict__ act, const float* __restrict__ wd,
    const int* __restrict__ offs, const int* __restrict__ slot_tok,
    const float* __restrict__ slot_w, float* __restrict__ out) {
  int e = blockIdx.y >> 4;
  int chunk = blockIdx.y & (CHUNKS_PER_E - 1);
  int lo = offs[e], hi = offs[e + 1];
  int row0 = lo + chunk * BM;
  if (row0 >= hi) return;
  int rows = min(BM, hi - row0);
  int h0 = blockIdx.x * BN;

  __shared__ short sA[BM * BK];
  __shared__ short sB[BN * BK];

  int tid = threadIdx.x;
  int lane = tid & 63;
  int wid = tid >> 6;
  int wm = wid >> 1, wn = wid & 1;
  int lr = lane & 15;
  int lk = (lane >> 4) * 8;

  const float* wdE = wd + (size_t)e * I_ * H_;

  f32x4 acc[4][2];
#pragma unroll
  for (int mr = 0; mr < 4; ++mr)
#pragma unroll
    for (int nr = 0; nr < 2; ++nr)
      acc[mr][nr] = (f32x4){0.f, 0.f, 0.f, 0.f};

  for (int k0 = 0; k0 < I_; k0 += BK) {
    __syncthreads();
    // stage A: 128x32 bf16 (already bf16, gathered slot rows)
#pragma unroll
    for (int it = 0; it < 2; ++it) {
      int idx = tid + it * 256;           // 0..511
      int r = idx >> 2;
      int c8 = (idx & 3) * 8;
      int gr = (r < rows) ? (row0 + r) : row0;
      *(bf16x8*)&sA[r * BK + c8] = *(const bf16x8*)&act[(size_t)gr * I_ + k0 + c8];
    }
    // stage B: 32x64 f32 -> bf16 transposed [h][k]
#pragma unroll
    for (int it = 0; it < 2; ++it) {
      int idx = tid + it * 256;
      int ir = idx >> 4;
      int h4 = (idx & 15) * 4;
      const float4 v = *(const float4*)&wdE[(size_t)(k0 + ir) * H_ + h0 + h4];
      sB[(h4 + 0) * BK + ir] = f2bf(v.x);
      sB[(h4 + 1) * BK + ir] = f2bf(v.y);
      sB[(h4 + 2) * BK + ir] = f2bf(v.z);
      sB[(h4 + 3) * BK + ir] = f2bf(v.w);
    }
    __syncthreads();

    bf16x8 a[4], b[2];
#pragma unroll
    for (int mr = 0; mr < 4; ++mr)
      a[mr] = *(const bf16x8*)&sA[(wm * 64 + mr * 16 + lr) * BK + lk];
#pragma unroll
    for (int nr = 0; nr < 2; ++nr)
      b[nr] = *(const bf16x8*)&sB[(wn * 32 + nr * 16 + lr) * BK + lk];
#pragma unroll
    for (int mr = 0; mr < 4; ++mr)
#pragma unroll
      for (int nr = 0; nr < 2; ++nr)
        acc[mr][nr] = __builtin_amdgcn_mfma_f32_16x16x32_bf16(a[mr], b[nr], acc[mr][nr], 0, 0, 0);
  }

  // epilogue: scale by combine weight, scatter-add to out
#pragma unroll
  for (int mr = 0; mr < 4; ++mr) {
#pragma unroll
    for (int r = 0; r < 4; ++r) {
      int m = wm * 64 + mr * 16 + (lane >> 4) * 4 + r;
      if (m < rows) {
        int gs = row0 + m;
        float wc = slot_w[gs];
        int tok = slot_tok[gs];
#pragma unroll
        for (int nr = 0; nr < 2; ++nr) {
          atomicAdd(&out[(size_t)tok * H_ + h0 + wn * 32 + nr * 16 + lr],
                    acc[mr][nr][r] * wc);
        }
      }
    }
  }
}

// ---------------------------------------------------------------------------
extern "C" void kernel_launch(void* const* d_in, const int* in_sizes, int n_in,
                              void* d_out, int out_size, void* d_ws, size_t ws_size,
                              hipStream_t stream) {
  const float* hs   = (const float*)d_in[0];
  const float* aff  = (const float*)d_in[1];
  const int*   eidx = (const int*)d_in[2];
  const float* wg   = (const float*)d_in[3];
  const float* wu   = (const float*)d_in[4];
  const float* wd   = (const float*)d_in[5];
  float* out = (float*)d_out;

  char* ws = (char*)d_ws;
  int*   offs     = (int*)ws;                          // 9 ints (64B reserved)
  int*   slot_tok = (int*)(ws + 64);                   // 2048 ints
  float* slot_w   = (float*)(ws + 64 + NSLOT * 4);     // 2048 floats
  short* act      = (short*)(ws + 64 + NSLOT * 8);     // 2048*2048 bf16 = 8MB

  hipMemsetAsync(d_out, 0, (size_t)out_size * sizeof(float), stream);
  k_build<<<1, T_, 0, stream>>>(aff, eidx, offs, slot_tok, slot_w);
  k_gemm1<<<dim3(I_ / BN, E_ * CHUNKS_PER_E), 256, 0, stream>>>(hs, wg, wu, offs, slot_tok, act);
  k_gemm2<<<dim3(H_ / BN, E_ * CHUNKS_PER_E), 256, 0, stream>>>(act, wd, offs, slot_tok, slot_w, out);
}

// Round 2
// 113.990 us; speedup vs baseline: 2.9675x; 2.9675x over previous
//
#include <hip/hip_runtime.h>
#include <hip/hip_bf16.h>
#include <math.h>

// Problem constants (fixed shape)
#define T_ 1024
#define H_ 1024
#define I_ 2048
#define E_ 8
#define TOPK_ 2
#define NSLOT 2048

// GEMM tiling
#define BM 128
#define BN 64
#define BK 32
#define CHUNKS_PER_E (NSLOT / BM)   // 16: worst-case capacity per expert
#define SPLITK2 4                    // gemm2 split-K factor (K=2048 -> 4x512)

typedef __attribute__((ext_vector_type(8))) short bf16x8;
typedef __attribute__((ext_vector_type(4))) short short4v;
typedef __attribute__((ext_vector_type(4))) float f32x4;

__device__ __forceinline__ short f2bf(float f) {
  union { float f; unsigned u; } v; v.f = f;
  unsigned r = v.u + 0x7FFFu + ((v.u >> 16) & 1u);   // round-to-nearest-even
  return (short)(r >> 16);
}
__device__ __forceinline__ unsigned pack2(float lo, float hi) {
  return (unsigned)(unsigned short)f2bf(lo) | ((unsigned)(unsigned short)f2bf(hi) << 16);
}

// Swizzled [n][k] bf16 B-tile addressing: rows of 64B (BK=32 bf16).
// byte(n,k) = n*64 + ((k*2) ^ (((n>>2)&3)<<4)).
// Writes (k-pairs, 4B) land 4-way; b128 fragment reads stay at the 8-quad floor.
__device__ __forceinline__ unsigned bswz(int n, int kbyte) {
  return (unsigned)(n * 64 + (kbyte ^ (((n >> 2) & 3) << 4)));
}

// ---------------------------------------------------------------------------
// Kernel 1: build compacted per-expert slot lists + normalized combine weights
// ---------------------------------------------------------------------------
__global__ __launch_bounds__(1024) void k_build(
    const float* __restrict__ aff, const int* __restrict__ eidx,
    int* __restrict__ offs, int* __restrict__ slot_tok, float* __restrict__ slot_w) {
  __shared__ int cnt[E_];
  __shared__ int soff[E_ + 1];
  int t = threadIdx.x;
  if (t < E_) cnt[t] = 0;
  __syncthreads();
  int e0 = eidx[t * 2 + 0];
  int e1 = eidx[t * 2 + 1];
  float a0 = aff[t * E_ + e0];
  float a1 = aff[t * E_ + e1];
  float inv = 1.0f / (a0 + a1);
  int r0 = atomicAdd(&cnt[e0], 1);
  int r1 = atomicAdd(&cnt[e1], 1);
  __syncthreads();
  if (t == 0) {
    int s = 0;
    for (int e = 0; e < E_; ++e) { soff[e] = s; s += cnt[e]; }
    soff[E_] = s;
  }
  __syncthreads();
  if (t <= E_) offs[t] = soff[t];
  int s0 = soff[e0] + r0;
  int s1 = soff[e1] + r1;
  slot_tok[s0] = t; slot_w[s0] = a0 * inv;
  slot_tok[s1] = t; slot_w[s1] = a1 * inv;
}

// ---------------------------------------------------------------------------
// Kernel 2: grouped GEMM  act[slot, i] = silu(X@Wg) * (X@Wu)  (bf16 out)
// ---------------------------------------------------------------------------
__global__ __launch_bounds__(256) void k_gemm1(
    const float* __restrict__ hs, const float* __restrict__ wg,
    const float* __restrict__ wu, const int* __restrict__ offs,
    const int* __restrict__ slot_tok, short* __restrict__ act) {
  int e = blockIdx.y >> 4;
  int chunk = blockIdx.y & (CHUNKS_PER_E - 1);
  int lo = offs[e], hi = offs[e + 1];
  int row0 = lo + chunk * BM;
  if (row0 >= hi) return;
  int rows = min(BM, hi - row0);
  int i0 = blockIdx.x * BN;

  __shared__ short sA[BM * BK];      // [row][k] row-major, 64B rows
  __shared__ short sBg[BN * BK];     // swizzled [n][k]
  __shared__ short sBu[BN * BK];

  int tid = threadIdx.x;
  int lane = tid & 63;
  int wid = tid >> 6;
  int wm = wid >> 1, wn = wid & 1;   // 2x2 wave grid, each wave 64x32
  int lr = lane & 15;
  int lk = (lane >> 4) * 8;

  const float* wgE = wg + (size_t)e * H_ * I_;
  const float* wuE = wu + (size_t)e * H_ * I_;

  f32x4 accg[4][2], accu[4][2];
#pragma unroll
  for (int mr = 0; mr < 4; ++mr)
#pragma unroll
    for (int nr = 0; nr < 2; ++nr) {
      accg[mr][nr] = (f32x4){0.f, 0.f, 0.f, 0.f};
      accu[mr][nr] = (f32x4){0.f, 0.f, 0.f, 0.f};
    }

  // A-staging geometry (k-invariant): 4 units of (row, col4)
  int atok[4];
#pragma unroll
  for (int it = 0; it < 4; ++it) {
    int idx = tid + it * 256;
    int r = idx >> 3;
    atok[it] = slot_tok[(r < rows) ? (row0 + r) : row0];
  }
  // B-staging geometry: one (k-pair u, n-quad) unit per thread
  int bu_ = tid >> 4;                // 0..15 -> k rows 2u, 2u+1
  int bn4 = (tid & 15) * 4;          // 0..60

  for (int k0 = 0; k0 < H_; k0 += BK) {
    // ---- issue global loads BEFORE the barrier (latency overlaps prev MFMA) --
    float4 aReg[4];
#pragma unroll
    for (int it = 0; it < 4; ++it) {
      int idx = tid + it * 256;
      int c4 = (idx & 7) * 4;
      aReg[it] = *(const float4*)&hs[(size_t)atok[it] * H_ + k0 + c4];
    }
    float4 g0 = *(const float4*)&wgE[(size_t)(k0 + 2 * bu_) * I_ + i0 + bn4];
    float4 g1 = *(const float4*)&wgE[(size_t)(k0 + 2 * bu_ + 1) * I_ + i0 + bn4];
    float4 u0 = *(const float4*)&wuE[(size_t)(k0 + 2 * bu_) * I_ + i0 + bn4];
    float4 u1 = *(const float4*)&wuE[(size_t)(k0 + 2 * bu_ + 1) * I_ + i0 + bn4];

    __syncthreads();   // prev iter's fragment reads complete

    // ---- LDS writes ----
#pragma unroll
    for (int it = 0; it < 4; ++it) {
      int idx = tid + it * 256;
      int r = idx >> 3;
      int c4 = (idx & 7) * 4;
      short4v s;
      s.x = f2bf(aReg[it].x); s.y = f2bf(aReg[it].y);
      s.z = f2bf(aReg[it].z); s.w = f2bf(aReg[it].w);
      *(short4v*)&sA[r * BK + c4] = s;
    }
    const float* g0p = (const float*)&g0; const float* g1p = (const float*)&g1;
    const float* u0p = (const float*)&u0; const float* u1p = (const float*)&u1;
#pragma unroll
    for (int j = 0; j < 4; ++j) {
      int n = bn4 + j;
      unsigned off = bswz(n, 4 * bu_);
      *(unsigned*)((char*)sBg + off) = pack2(g0p[j], g1p[j]);
      *(unsigned*)((char*)sBu + off) = pack2(u0p[j], u1p[j]);
    }
    __syncthreads();

    // ---- fragments + MFMA ----
    bf16x8 a[4], bg[2], bu[2];
#pragma unroll
    for (int mr = 0; mr < 4; ++mr)
      a[mr] = *(const bf16x8*)&sA[(wm * 64 + mr * 16 + lr) * BK + lk];
#pragma unroll
    for (int nr = 0; nr < 2; ++nr) {
      int col = wn * 32 + nr * 16 + lr;
      unsigned off = bswz(col, lk * 2);
      bg[nr] = *(const bf16x8*)((const char*)sBg + off);
      bu[nr] = *(const bf16x8*)((const char*)sBu + off);
    }
#pragma unroll
    for (int mr = 0; mr < 4; ++mr)
#pragma unroll
      for (int nr = 0; nr < 2; ++nr) {
        accg[mr][nr] = __builtin_amdgcn_mfma_f32_16x16x32_bf16(a[mr], bg[nr], accg[mr][nr], 0, 0, 0);
        accu[mr][nr] = __builtin_amdgcn_mfma_f32_16x16x32_bf16(a[mr], bu[nr], accu[mr][nr], 0, 0, 0);
      }
  }

  // epilogue: silu(g)*u -> bf16 act
#pragma unroll
  for (int mr = 0; mr < 4; ++mr) {
#pragma unroll
    for (int r = 0; r < 4; ++r) {
      int m = wm * 64 + mr * 16 + (lane >> 4) * 4 + r;
      if (m < rows) {
#pragma unroll
        for (int nr = 0; nr < 2; ++nr) {
          float g = accg[mr][nr][r];
          float u = accu[mr][nr][r];
          float sg = 1.0f / (1.0f + __expf(-g));
          int icol = i0 + wn * 32 + nr * 16 + lr;
          act[(size_t)(row0 + m) * I_ + icol] = f2bf(g * sg * u);
        }
      }
    }
  }
}

// ---------------------------------------------------------------------------
// Kernel 3: grouped GEMM  out[tok, h] += combine_w * (act[slot,:] @ Wd[e])
// Split-K x4 over I, atomicAdd combine into out.
// ---------------------------------------------------------------------------
__global__ __launch_bounds__(256) void k_gemm2(
    const short* __restrict__ act, const float* __restrict__ wd,
    const int* __restrict__ offs, const int* __restrict__ slot_tok,
    const float* __restrict__ slot_w, float* __restrict__ out) {
  int e = blockIdx.y >> 4;
  int chunk = blockIdx.y & (CHUNKS_PER_E - 1);
  int lo = offs[e], hi = offs[e + 1];
  int row0 = lo + chunk * BM;
  if (row0 >= hi) return;
  int rows = min(BM, hi - row0);
  int h0 = blockIdx.x * BN;
  int kbase = blockIdx.z * (I_ / SPLITK2);
  int kend = kbase + (I_ / SPLITK2);

  __shared__ short sA[BM * BK];      // [row][k] row-major
  __shared__ short sB[BN * BK];      // swizzled [n][k]

  int tid = threadIdx.x;
  int lane = tid & 63;
  int wid = tid >> 6;
  int wm = wid >> 1, wn = wid & 1;
  int lr = lane & 15;
  int lk = (lane >> 4) * 8;

  const float* wdE = wd + (size_t)e * I_ * H_;

  f32x4 acc[4][2];
#pragma unroll
  for (int mr = 0; mr < 4; ++mr)
#pragma unroll
    for (int nr = 0; nr < 2; ++nr)
      acc[mr][nr] = (f32x4){0.f, 0.f, 0.f, 0.f};

  // A-staging rows (k-invariant)
  int agr[2];
#pragma unroll
  for (int it = 0; it < 2; ++it) {
    int idx = tid + it * 256;
    int r = idx >> 2;
    agr[it] = (r < rows) ? (row0 + r) : row0;
  }
  int bu_ = tid >> 4;
  int bn4 = (tid & 15) * 4;

  for (int k0 = kbase; k0 < kend; k0 += BK) {
    // ---- global loads first ----
    bf16x8 aReg[2];
#pragma unroll
    for (int it = 0; it < 2; ++it) {
      int idx = tid + it * 256;
      int c8 = (idx & 3) * 8;
      aReg[it] = *(const bf16x8*)&act[(size_t)agr[it] * I_ + k0 + c8];
    }
    float4 b0 = *(const float4*)&wdE[(size_t)(k0 + 2 * bu_) * H_ + h0 + bn4];
    float4 b1 = *(const float4*)&wdE[(size_t)(k0 + 2 * bu_ + 1) * H_ + h0 + bn4];

    __syncthreads();

    // ---- LDS writes ----
#pragma unroll
    for (int it = 0; it < 2; ++it) {
      int idx = tid + it * 256;
      int r = idx >> 2;
      int c8 = (idx & 3) * 8;
      *(bf16x8*)&sA[r * BK + c8] = aReg[it];
    }
    const float* b0p = (const float*)&b0; const float* b1p = (const float*)&b1;
#pragma unroll
    for (int j = 0; j < 4; ++j) {
      int n = bn4 + j;
      *(unsigned*)((char*)sB + bswz(n, 4 * bu_)) = pack2(b0p[j], b1p[j]);
    }
    __syncthreads();

    // ---- fragments + MFMA ----
    bf16x8 a[4], b[2];
#pragma unroll
    for (int mr = 0; mr < 4; ++mr)
      a[mr] = *(const bf16x8*)&sA[(wm * 64 + mr * 16 + lr) * BK + lk];
#pragma unroll
    for (int nr = 0; nr < 2; ++nr) {
      int col = wn * 32 + nr * 16 + lr;
      b[nr] = *(const bf16x8*)((const char*)sB + bswz(col, lk * 2));
    }
#pragma unroll
    for (int mr = 0; mr < 4; ++mr)
#pragma unroll
      for (int nr = 0; nr < 2; ++nr)
        acc[mr][nr] = __builtin_amdgcn_mfma_f32_16x16x32_bf16(a[mr], b[nr], acc[mr][nr], 0, 0, 0);
  }

  // epilogue: scale by combine weight, scatter-add to out
#pragma unroll
  for (int mr = 0; mr < 4; ++mr) {
#pragma unroll
    for (int r = 0; r < 4; ++r) {
      int m = wm * 64 + mr * 16 + (lane >> 4) * 4 + r;
      if (m < rows) {
        int gs = row0 + m;
        float wc = slot_w[gs];
        int tok = slot_tok[gs];
#pragma unroll
        for (int nr = 0; nr < 2; ++nr) {
          atomicAdd(&out[(size_t)tok * H_ + h0 + wn * 32 + nr * 16 + lr],
                    acc[mr][nr][r] * wc);
        }
      }
    }
  }
}

// ---------------------------------------------------------------------------
extern "C" void kernel_launch(void* const* d_in, const int* in_sizes, int n_in,
                              void* d_out, int out_size, void* d_ws, size_t ws_size,
                              hipStream_t stream) {
  const float* hs   = (const float*)d_in[0];
  const float* aff  = (const float*)d_in[1];
  const int*   eidx = (const int*)d_in[2];
  const float* wg   = (const float*)d_in[3];
  const float* wu   = (const float*)d_in[4];
  const float* wd   = (const float*)d_in[5];
  float* out = (float*)d_out;

  char* ws = (char*)d_ws;
  int*   offs     = (int*)ws;                          // 9 ints (64B reserved)
  int*   slot_tok = (int*)(ws + 64);                   // 2048 ints
  float* slot_w   = (float*)(ws + 64 + NSLOT * 4);     // 2048 floats
  short* act      = (short*)(ws + 64 + NSLOT * 8);     // 2048*2048 bf16 = 8MB

  hipMemsetAsync(d_out, 0, (size_t)out_size * sizeof(float), stream);
  k_build<<<1, T_, 0, stream>>>(aff, eidx, offs, slot_tok, slot_w);
  k_gemm1<<<dim3(I_ / BN, E_ * CHUNKS_PER_E), 256, 0, stream>>>(hs, wg, wu, offs, slot_tok, act);
  k_gemm2<<<dim3(H_ / BN, E_ * CHUNKS_PER_E, SPLITK2), 256, 0, stream>>>(act, wd, offs, slot_tok, slot_w, out);
}

// Round 3
// 111.111 us; speedup vs baseline: 3.0444x; 1.0259x over previous
//
#include <hip/hip_runtime.h>
#include <hip/hip_bf16.h>
#include <math.h>

// Problem constants (fixed shape)
#define T_ 1024
#define H_ 1024
#define I_ 2048
#define E_ 8
#define TOPK_ 2
#define NSLOT 2048

// GEMM tiling
#define BM 128
#define BN 64
#define BK 32
#define CHUNKS_PER_E (NSLOT / BM)   // 16
#define SPLITK2 2                    // gemm2 split-K (I=2048 -> 2x1024)

typedef __attribute__((ext_vector_type(8))) short bf16x8;
typedef __attribute__((ext_vector_type(4))) float f32x4;
typedef __attribute__((ext_vector_type(4))) unsigned uint4v;

__device__ __forceinline__ short f2bf(float f) {
  union { float f; unsigned u; } v; v.f = f;
  unsigned r = v.u + 0x7FFFu + ((v.u >> 16) & 1u);
  return (short)(r >> 16);
}
// HW packed convert: low16 = bf16(lo), high16 = bf16(hi)
__device__ __forceinline__ unsigned cvtpk(float lo, float hi) {
  unsigned r;
  asm("v_cvt_pk_bf16_f32 %0, %1, %2" : "=v"(r) : "v"(lo), "v"(hi));
  return r;
}
// async 16B global->LDS (lane i writes lds_base + i*16)
__device__ __forceinline__ void gll16(const void* g, void* l) {
  __builtin_amdgcn_global_load_lds(
      (const __attribute__((address_space(1))) void*)g,
      (__attribute__((address_space(3))) void*)l, 16, 0, 0);
}

// Swizzled [n][k] bf16 B-tile: rows of 64B (BK=32 bf16).
// byte(n,kbyte) = n*64 + (kbyte ^ (((n>>2)&3)<<4)). 4B transpose-writes 4-way;
// b128 fragment reads at the 8-cycle floor (bank-enumerated).
__device__ __forceinline__ unsigned bswz(int n, int kbyte) {
  return (unsigned)(n * 64 + (kbyte ^ (((n >> 2) & 3) << 4)));
}

// ---------------------------------------------------------------------------
// Kernel 0: hs f32 -> bf16 (one-time, memory-bound)
// ---------------------------------------------------------------------------
__global__ __launch_bounds__(256) void k_prep(const float* __restrict__ hs,
                                              short* __restrict__ hs_bf) {
  int i = (blockIdx.x * 256 + threadIdx.x) * 8;
  float4 v0 = *(const float4*)&hs[i];
  float4 v1 = *(const float4*)&hs[i + 4];
  uint4v p;
  p.x = cvtpk(v0.x, v0.y); p.y = cvtpk(v0.z, v0.w);
  p.z = cvtpk(v1.x, v1.y); p.w = cvtpk(v1.z, v1.w);
  *(uint4v*)&hs_bf[i] = p;
}

// ---------------------------------------------------------------------------
// Kernel 1: build compacted per-expert slot lists + normalized combine weights
// ---------------------------------------------------------------------------
__global__ __launch_bounds__(1024) void k_build(
    const float* __restrict__ aff, const int* __restrict__ eidx,
    int* __restrict__ offs, int* __restrict__ slot_tok, float* __restrict__ slot_w) {
  __shared__ int cnt[E_];
  __shared__ int soff[E_ + 1];
  int t = threadIdx.x;
  if (t < E_) cnt[t] = 0;
  __syncthreads();
  int e0 = eidx[t * 2 + 0];
  int e1 = eidx[t * 2 + 1];
  float a0 = aff[t * E_ + e0];
  float a1 = aff[t * E_ + e1];
  float inv = 1.0f / (a0 + a1);
  int r0 = atomicAdd(&cnt[e0], 1);
  int r1 = atomicAdd(&cnt[e1], 1);
  __syncthreads();
  if (t == 0) {
    int s = 0;
    for (int e = 0; e < E_; ++e) { soff[e] = s; s += cnt[e]; }
    soff[E_] = s;
  }
  __syncthreads();
  if (t <= E_) offs[t] = soff[t];
  int s0 = soff[e0] + r0;
  int s1 = soff[e1] + r1;
  slot_tok[s0] = t; slot_w[s0] = a0 * inv;
  slot_tok[s1] = t; slot_w[s1] = a1 * inv;
}

// ---------------------------------------------------------------------------
// Kernel 2: grouped GEMM  act[slot,i] = silu(X@Wg) * (X@Wu)
// 512 thr (8 waves, 4m x 2n, wave-tile 32x32); A via global_load_lds (bf16 hs);
// weights f32 -> cvt_pk staged; double-buffered LDS, 1 barrier/iter.
// ---------------------------------------------------------------------------
__global__ __launch_bounds__(512, 4) void k_gemm1(
    const short* __restrict__ hs_bf, const float* __restrict__ wg,
    const float* __restrict__ wu, const int* __restrict__ offs,
    const int* __restrict__ slot_tok, short* __restrict__ act) {
  int e = blockIdx.y >> 4;
  int chunk = blockIdx.y & (CHUNKS_PER_E - 1);
  int lo = offs[e], hi = offs[e + 1];
  int row0 = lo + chunk * BM;
  if (row0 >= hi) return;
  int rows = min(BM, hi - row0);
  int i0 = blockIdx.x * BN;

  __shared__ short sA[2][BM * BK];       // [buf][row][k] 64B rows
  __shared__ short sB[2][2][BN * BK];    // [buf][g|u][swizzled n,k]

  int tid = threadIdx.x;
  int lane = tid & 63;
  int w = tid >> 6;                 // 0..7
  int wm = w >> 1, wn = w & 1;      // 4m x 2n
  int lr = lane & 15;
  int lk = (lane >> 4) * 8;

  const float* wgE = wg + (size_t)e * H_ * I_;
  const float* wuE = wu + (size_t)e * H_ * I_;

  // A gll geometry: wave w stages rows [16w,16w+16); lane i -> row 16w+(i>>2)
  int ra = 16 * w + (lane >> 2);
  int tokA = slot_tok[row0 + min(ra, rows - 1)];
  const short* srcA = hs_bf + (size_t)tokA * H_ + (lane & 3) * 8;
  // B geometry: waves 0-3 stage gate, 4-7 stage up; per wave 4 k-pairs x 64 n
  const float* wB = (w < 4) ? wgE : wuE;
  int mat = (w >= 4);
  int up = 4 * (w & 3) + (lane >> 4);   // k-pair 0..15
  int n4 = (lane & 15) * 4;
  const float* srcB = wB + (size_t)(2 * up) * I_ + i0 + n4;

  f32x4 accg[2][2], accu[2][2];
#pragma unroll
  for (int mr = 0; mr < 2; ++mr)
#pragma unroll
    for (int nr = 0; nr < 2; ++nr) {
      accg[mr][nr] = (f32x4){0.f, 0.f, 0.f, 0.f};
      accu[mr][nr] = (f32x4){0.f, 0.f, 0.f, 0.f};
    }

  // ---- prologue: stage tile 0 into buf 0 ----
  gll16(srcA, &sA[0][w * 512]);
  {
    float4 b0 = *(const float4*)srcB;
    float4 b1 = *(const float4*)(srcB + I_);
    const float* b0p = &b0.x; const float* b1p = &b1.x;
#pragma unroll
    for (int j = 0; j < 4; ++j)
      *(unsigned*)((char*)&sB[0][mat][0] + bswz(n4 + j, 4 * up)) = cvtpk(b0p[j], b1p[j]);
  }
  __syncthreads();

  int buf = 0;
  const int NT = H_ / BK;   // 32
  for (int t = 0; t < NT; ++t) {
    float4 b0, b1;
    int has_next = (t + 1 < NT);
    if (has_next) {
      int k1 = (t + 1) * BK;
      gll16(srcA + k1, &sA[buf ^ 1][w * 512]);
      b0 = *(const float4*)(srcB + (size_t)k1 * I_);
      b1 = *(const float4*)(srcB + (size_t)(k1 + 1) * I_);
    }
    // ---- fragments + MFMA from buf ----
    bf16x8 a[2], bg[2], bu[2];
#pragma unroll
    for (int mr = 0; mr < 2; ++mr)
      a[mr] = *(const bf16x8*)&sA[buf][(wm * 32 + mr * 16 + lr) * BK + lk];
#pragma unroll
    for (int nr = 0; nr < 2; ++nr) {
      int col = wn * 32 + nr * 16 + lr;
      unsigned off = bswz(col, lk * 2);
      bg[nr] = *(const bf16x8*)((const char*)&sB[buf][0][0] + off);
      bu[nr] = *(const bf16x8*)((const char*)&sB[buf][1][0] + off);
    }
#pragma unroll
    for (int mr = 0; mr < 2; ++mr)
#pragma unroll
      for (int nr = 0; nr < 2; ++nr) {
        accg[mr][nr] = __builtin_amdgcn_mfma_f32_16x16x32_bf16(a[mr], bg[nr], accg[mr][nr], 0, 0, 0);
        accu[mr][nr] = __builtin_amdgcn_mfma_f32_16x16x32_bf16(a[mr], bu[nr], accu[mr][nr], 0, 0, 0);
      }
    // ---- convert+write next B tile ----
    if (has_next) {
      const float* b0p = &b0.x; const float* b1p = &b1.x;
#pragma unroll
      for (int j = 0; j < 4; ++j)
        *(unsigned*)((char*)&sB[buf ^ 1][mat][0] + bswz(n4 + j, 4 * up)) = cvtpk(b0p[j], b1p[j]);
    }
    __syncthreads();   // implicit vmcnt(0)+lgkmcnt(0) drain covers the gll
    buf ^= 1;
  }

  // ---- epilogue: silu(g)*u -> bf16 act ----
#pragma unroll
  for (int mr = 0; mr < 2; ++mr) {
#pragma unroll
    for (int r = 0; r < 4; ++r) {
      int m = wm * 32 + mr * 16 + (lane >> 4) * 4 + r;
      if (m < rows) {
#pragma unroll
        for (int nr = 0; nr < 2; ++nr) {
          float g = accg[mr][nr][r];
          float u = accu[mr][nr][r];
          float sg = 1.0f / (1.0f + __expf(-g));
          act[(size_t)(row0 + m) * I_ + i0 + wn * 32 + nr * 16 + lr] = f2bf(g * sg * u);
        }
      }
    }
  }
}

// ---------------------------------------------------------------------------
// Kernel 3: grouped GEMM  out[tok,h] += w * (act[slot,:] @ Wd[e]); split-K x2
// ---------------------------------------------------------------------------
__global__ __launch_bounds__(512, 4) void k_gemm2(
    const short* __restrict__ act, const float* __restrict__ wd,
    const int* __restrict__ offs, const int* __restrict__ slot_tok,
    const float* __restrict__ slot_w, float* __restrict__ out) {
  int e = blockIdx.y >> 4;
  int chunk = blockIdx.y & (CHUNKS_PER_E - 1);
  int lo = offs[e], hi = offs[e + 1];
  int row0 = lo + chunk * BM;
  if (row0 >= hi) return;
  int rows = min(BM, hi - row0);
  int h0 = blockIdx.x * BN;
  int kbase = blockIdx.z * (I_ / SPLITK2);

  __shared__ short sA[2][BM * BK];
  __shared__ short sB[2][BN * BK];

  int tid = threadIdx.x;
  int lane = tid & 63;
  int w = tid >> 6;
  int wm = w >> 1, wn = w & 1;
  int lr = lane & 15;
  int lk = (lane >> 4) * 8;

  const float* wdE = wd + (size_t)e * I_ * H_;

  // A gll geometry: rows contiguous slots (no gather)
  int ra = min(16 * w + (lane >> 2), rows - 1);
  const short* srcA = act + (size_t)(row0 + ra) * I_ + kbase + (lane & 3) * 8;
  // B geometry: 512 thr, per thread 1 k-pair x 2 cols
  int up = tid >> 5;                   // k-pair 0..15
  int n2 = (tid & 31) * 2;
  const float* srcB = wdE + (size_t)(kbase + 2 * up) * H_ + h0 + n2;

  f32x4 acc[2][2];
#pragma unroll
  for (int mr = 0; mr < 2; ++mr)
#pragma unroll
    for (int nr = 0; nr < 2; ++nr)
      acc[mr][nr] = (f32x4){0.f, 0.f, 0.f, 0.f};

  // prologue
  gll16(srcA, &sA[0][w * 512]);
  {
    float2 r0 = *(const float2*)srcB;
    float2 r1 = *(const float2*)(srcB + H_);
    *(unsigned*)((char*)&sB[0][0] + bswz(n2, 4 * up))     = cvtpk(r0.x, r1.x);
    *(unsigned*)((char*)&sB[0][0] + bswz(n2 + 1, 4 * up)) = cvtpk(r0.y, r1.y);
  }
  __syncthreads();

  int buf = 0;
  const int NT = (I_ / SPLITK2) / BK;   // 32
  for (int t = 0; t < NT; ++t) {
    float2 r0, r1;
    int has_next = (t + 1 < NT);
    if (has_next) {
      int k1 = (t + 1) * BK;
      gll16(srcA + k1, &sA[buf ^ 1][w * 512]);
      r0 = *(const float2*)(srcB + (size_t)k1 * H_);
      r1 = *(const float2*)(srcB + (size_t)(k1 + 1) * H_);
    }
    bf16x8 a[2], b[2];
#pragma unroll
    for (int mr = 0; mr < 2; ++mr)
      a[mr] = *(const bf16x8*)&sA[buf][(wm * 32 + mr * 16 + lr) * BK + lk];
#pragma unroll
    for (int nr = 0; nr < 2; ++nr)
      b[nr] = *(const bf16x8*)((const char*)&sB[buf][0] + bswz(wn * 32 + nr * 16 + lr, lk * 2));
#pragma unroll
    for (int mr = 0; mr < 2; ++mr)
#pragma unroll
      for (int nr = 0; nr < 2; ++nr)
        acc[mr][nr] = __builtin_amdgcn_mfma_f32_16x16x32_bf16(a[mr], b[nr], acc[mr][nr], 0, 0, 0);
    if (has_next) {
      *(unsigned*)((char*)&sB[buf ^ 1][0] + bswz(n2, 4 * up))     = cvtpk(r0.x, r1.x);
      *(unsigned*)((char*)&sB[buf ^ 1][0] + bswz(n2 + 1, 4 * up)) = cvtpk(r0.y, r1.y);
    }
    __syncthreads();
    buf ^= 1;
  }

  // epilogue: scale by combine weight, scatter-add
#pragma unroll
  for (int mr = 0; mr < 2; ++mr) {
#pragma unroll
    for (int r = 0; r < 4; ++r) {
      int m = wm * 32 + mr * 16 + (lane >> 4) * 4 + r;
      if (m < rows) {
        int gs = row0 + m;
        float wc = slot_w[gs];
        int tok = slot_tok[gs];
#pragma unroll
        for (int nr = 0; nr < 2; ++nr)
          atomicAdd(&out[(size_t)tok * H_ + h0 + wn * 32 + nr * 16 + lr],
                    acc[mr][nr][r] * wc);
      }
    }
  }
}

// ---------------------------------------------------------------------------
extern "C" void kernel_launch(void* const* d_in, const int* in_sizes, int n_in,
                              void* d_out, int out_size, void* d_ws, size_t ws_size,
                              hipStream_t stream) {
  const float* hs   = (const float*)d_in[0];
  const float* aff  = (const float*)d_in[1];
  const int*   eidx = (const int*)d_in[2];
  const float* wg   = (const float*)d_in[3];
  const float* wu   = (const float*)d_in[4];
  const float* wd   = (const float*)d_in[5];
  float* out = (float*)d_out;

  char* ws = (char*)d_ws;
  int*   offs     = (int*)ws;                            // 64B reserved
  int*   slot_tok = (int*)(ws + 64);                     // 2048 ints
  float* slot_w   = (float*)(ws + 64 + NSLOT * 4);       // 2048 floats
  short* hs_bf    = (short*)(ws + 64 + NSLOT * 8);       // 2MB bf16 hs
  short* act      = (short*)(ws + 64 + NSLOT * 8 + (size_t)T_ * H_ * 2);  // 8MB

  hipMemsetAsync(d_out, 0, (size_t)out_size * sizeof(float), stream);
  k_build<<<1, T_, 0, stream>>>(aff, eidx, offs, slot_tok, slot_w);
  k_prep<<<(T_ * H_) / (256 * 8), 256, 0, stream>>>(hs, hs_bf);
  k_gemm1<<<dim3(I_ / BN, E_ * CHUNKS_PER_E), 512, 0, stream>>>(hs_bf, wg, wu, offs, slot_tok, act);
  k_gemm2<<<dim3(H_ / BN, E_ * CHUNKS_PER_E, SPLITK2), 512, 0, stream>>>(act, wd, offs, slot_tok, slot_w, out);
}

// Round 4
// 105.519 us; speedup vs baseline: 3.2058x; 1.0530x over previous
//
#include <hip/hip_runtime.h>
#include <hip/hip_bf16.h>
#include <math.h>

// Problem constants (fixed shape)
#define T_ 1024
#define H_ 1024
#define I_ 2048
#define E_ 8
#define NSLOT 2048

// GEMM tiling
#define BM 128
#define BN 64
#define BK 32
#define CHUNKS_PER_E (NSLOT / BM)   // 16
#define SPLITK2 2                    // gemm2 split-K (I=2048 -> 2x1024)

typedef __attribute__((ext_vector_type(8))) short bf16x8;
typedef __attribute__((ext_vector_type(4))) float f32x4;
typedef __attribute__((ext_vector_type(4))) unsigned uint4v;

#define MFMA_BF16 __builtin_amdgcn_mfma_f32_16x16x32_bf16

__device__ __forceinline__ short f2bf(float f) {
  union { float f; unsigned u; } v; v.f = f;
  unsigned r = v.u + 0x7FFFu + ((v.u >> 16) & 1u);
  return (short)(r >> 16);
}
// HW packed convert: low16 = bf16(lo), high16 = bf16(hi)
__device__ __forceinline__ unsigned cvtpk(float lo, float hi) {
  unsigned r;
  asm("v_cvt_pk_bf16_f32 %0, %1, %2" : "=v"(r) : "v"(lo), "v"(hi));
  return r;
}
// async 16B global->LDS (lane i writes lds_base + i*16)
__device__ __forceinline__ void gll16(const void* g, void* l) {
  __builtin_amdgcn_global_load_lds(
      (const __attribute__((address_space(1))) void*)g,
      (__attribute__((address_space(3))) void*)l, 16, 0, 0);
}

// Pipelined barrier: wait own LDS ops + allow up to 3 vmem (the t+2 tile's
// 1 gll + 2 B loads) to stay in flight across the barrier. vmcnt(3) always
// retires gll(t+1) (worst-case 4 outstanding, gll(t+1) oldest).
__device__ __forceinline__ void pipe_barrier() {
  __builtin_amdgcn_sched_barrier(0);
  asm volatile("s_waitcnt vmcnt(3) lgkmcnt(0)" ::: "memory");
  __builtin_amdgcn_s_barrier();
  __builtin_amdgcn_sched_barrier(0);
}
__device__ __forceinline__ void drain_barrier() {
  __builtin_amdgcn_sched_barrier(0);
  asm volatile("s_waitcnt vmcnt(0) lgkmcnt(0)" ::: "memory");
  __builtin_amdgcn_s_barrier();
  __builtin_amdgcn_sched_barrier(0);
}

// Swizzled [n][k] bf16 B-tile: rows of 64B (BK=32 bf16).
// byte(n,kbyte) = n*64 + (kbyte ^ (((n>>2)&3)<<4)).
__device__ __forceinline__ unsigned bswz(int n, int kbyte) {
  return (unsigned)(n * 64 + (kbyte ^ (((n >> 2) & 3) << 4)));
}

// ---------------------------------------------------------------------------
// Kernel 0: hs f32 -> bf16 (one-time, memory-bound)
// ---------------------------------------------------------------------------
__global__ __launch_bounds__(256) void k_prep(const float* __restrict__ hs,
                                              short* __restrict__ hs_bf) {
  int i = (blockIdx.x * 256 + threadIdx.x) * 8;
  float4 v0 = *(const float4*)&hs[i];
  float4 v1 = *(const float4*)&hs[i + 4];
  uint4v p;
  p.x = cvtpk(v0.x, v0.y); p.y = cvtpk(v0.z, v0.w);
  p.z = cvtpk(v1.x, v1.y); p.w = cvtpk(v1.z, v1.w);
  *(uint4v*)&hs_bf[i] = p;
}

// ---------------------------------------------------------------------------
// Kernel 1: build compacted per-expert slot lists + normalized combine weights
// ---------------------------------------------------------------------------
__global__ __launch_bounds__(1024) void k_build(
    const float* __restrict__ aff, const int* __restrict__ eidx,
    int* __restrict__ offs, int* __restrict__ slot_tok, float* __restrict__ slot_w) {
  __shared__ int cnt[E_];
  __shared__ int soff[E_ + 1];
  int t = threadIdx.x;
  if (t < E_) cnt[t] = 0;
  __syncthreads();
  int e0 = eidx[t * 2 + 0];
  int e1 = eidx[t * 2 + 1];
  float a0 = aff[t * E_ + e0];
  float a1 = aff[t * E_ + e1];
  float inv = 1.0f / (a0 + a1);
  int r0 = atomicAdd(&cnt[e0], 1);
  int r1 = atomicAdd(&cnt[e1], 1);
  __syncthreads();
  if (t == 0) {
    int s = 0;
    for (int e = 0; e < E_; ++e) { soff[e] = s; s += cnt[e]; }
    soff[E_] = s;
  }
  __syncthreads();
  if (t <= E_) offs[t] = soff[t];
  int s0 = soff[e0] + r0;
  int s1 = soff[e1] + r1;
  slot_tok[s0] = t; slot_w[s0] = a0 * inv;
  slot_tok[s1] = t; slot_w[s1] = a1 * inv;
}

// ---------------------------------------------------------------------------
// Kernel 2: grouped GEMM  act[slot,i] = silu(X@Wg) * (X@Wu)
// 512 thr (8 waves, 4m x 2n). Depth-2 counted-vmcnt pipeline:
// sA ring-4 (gll), sB ring-2 (reg-staged f32->cvt_pk), unroll 4.
// ---------------------------------------------------------------------------
__global__ __launch_bounds__(512, 4) void k_gemm1(
    const short* __restrict__ hs_bf, const float* __restrict__ wg,
    const float* __restrict__ wu, const int* __restrict__ offs,
    const int* __restrict__ slot_tok, short* __restrict__ act) {
  int e = blockIdx.y >> 4;
  int chunk = blockIdx.y & (CHUNKS_PER_E - 1);
  int lo = offs[e], hi = offs[e + 1];
  int row0 = lo + chunk * BM;
  if (row0 >= hi) return;
  int rows = min(BM, hi - row0);
  int i0 = blockIdx.x * BN;

  __shared__ short sA[4][BM * BK];       // ring-4, [row][k] 64B rows
  __shared__ short sB[2][2][BN * BK];    // ring-2 x {gate,up}, swizzled [n][k]

  int tid = threadIdx.x;
  int lane = tid & 63;
  int w = tid >> 6;                 // 0..7
  int wm = w >> 1, wn = w & 1;      // 4m x 2n
  int lr = lane & 15;
  int lk = (lane >> 4) * 8;

  const float* wgE = wg + (size_t)e * H_ * I_;
  const float* wuE = wu + (size_t)e * H_ * I_;

  // A gll geometry: wave w stages rows [16w,16w+16)
  int ra = 16 * w + (lane >> 2);
  int tokA = slot_tok[row0 + min(ra, rows - 1)];
  const short* srcA = hs_bf + (size_t)tokA * H_ + (lane & 3) * 8;
  // B geometry: waves 0-3 stage gate, 4-7 up; per thread 1 k-pair x 4 n
  const float* wB = (w < 4) ? wgE : wuE;
  int mat = (w >= 4);
  int up = 4 * (w & 3) + (lane >> 4);   // k-pair 0..15
  int n4 = (lane & 15) * 4;
  const float* srcB = wB + (size_t)(2 * up) * I_ + i0 + n4;

  f32x4 accg[2][2], accu[2][2];
#pragma unroll
  for (int mr = 0; mr < 2; ++mr)
#pragma unroll
    for (int nr = 0; nr < 2; ++nr) {
      accg[mr][nr] = (f32x4){0.f, 0.f, 0.f, 0.f};
      accu[mr][nr] = (f32x4){0.f, 0.f, 0.f, 0.f};
    }

  float4 bs[2][2];   // two B-reg sets (tiles t+1, t+2), static-indexed

  // ---- prologue: tiles 0,1 in flight; convert tile 0; full drain once ----
  gll16(srcA, &sA[0][w * 512]);
  bs[0][0] = *(const float4*)srcB;
  bs[0][1] = *(const float4*)(srcB + I_);
  gll16(srcA + BK, &sA[1][w * 512]);
  bs[1][0] = *(const float4*)(srcB + (size_t)BK * I_);
  bs[1][1] = *(const float4*)(srcB + (size_t)(BK + 1) * I_);
  {
    const float* p0 = (const float*)&bs[0][0];
    const float* p1 = (const float*)&bs[0][1];
#pragma unroll
    for (int j = 0; j < 4; ++j)
      *(unsigned*)((char*)&sB[0][mat][0] + bswz(n4 + j, 4 * up)) = cvtpk(p0[j], p1[j]);
  }
  drain_barrier();

  const int NT = H_ / BK;   // 32

#define G1_ITER(U, base_) do {                                                 \
    int t_ = (base_) + (U);                                                    \
    if (t_ + 2 < NT) {                                                         \
      int k2 = (t_ + 2) * BK;                                                  \
      gll16(srcA + k2, &sA[((U) + 2) & 3][w * 512]);                           \
      bs[(U) & 1][0] = *(const float4*)(srcB + (size_t)k2 * I_);               \
      bs[(U) & 1][1] = *(const float4*)(srcB + (size_t)(k2 + 1) * I_);         \
    }                                                                          \
    bf16x8 a0 = *(const bf16x8*)&sA[(U)][(wm * 32 + lr) * BK + lk];            \
    bf16x8 a1 = *(const bf16x8*)&sA[(U)][(wm * 32 + 16 + lr) * BK + lk];       \
    unsigned off0 = bswz(wn * 32 + lr, lk * 2);                                \
    unsigned off1 = bswz(wn * 32 + 16 + lr, lk * 2);                           \
    bf16x8 bg0 = *(const bf16x8*)((const char*)&sB[(U) & 1][0][0] + off0);     \
    bf16x8 bg1 = *(const bf16x8*)((const char*)&sB[(U) & 1][0][0] + off1);     \
    bf16x8 bu0 = *(const bf16x8*)((const char*)&sB[(U) & 1][1][0] + off0);     \
    bf16x8 bu1 = *(const bf16x8*)((const char*)&sB[(U) & 1][1][0] + off1);     \
    accg[0][0] = MFMA_BF16(a0, bg0, accg[0][0], 0, 0, 0);                      \
    accg[0][1] = MFMA_BF16(a0, bg1, accg[0][1], 0, 0, 0);                      \
    accg[1][0] = MFMA_BF16(a1, bg0, accg[1][0], 0, 0, 0);                      \
    accg[1][1] = MFMA_BF16(a1, bg1, accg[1][1], 0, 0, 0);                      \
    accu[0][0] = MFMA_BF16(a0, bu0, accu[0][0], 0, 0, 0);                      \
    accu[0][1] = MFMA_BF16(a0, bu1, accu[0][1], 0, 0, 0);                      \
    accu[1][0] = MFMA_BF16(a1, bu0, accu[1][0], 0, 0, 0);                      \
    accu[1][1] = MFMA_BF16(a1, bu1, accu[1][1], 0, 0, 0);                      \
    if (t_ + 1 < NT) {                                                         \
      const float* p0 = (const float*)&bs[((U) + 1) & 1][0];                   \
      const float* p1 = (const float*)&bs[((U) + 1) & 1][1];                   \
      _Pragma("unroll")                                                        \
      for (int j = 0; j < 4; ++j)                                              \
        *(unsigned*)((char*)&sB[((U) + 1) & 1][mat][0] + bswz(n4 + j, 4 * up)) \
            = cvtpk(p0[j], p1[j]);                                             \
    }                                                                          \
    pipe_barrier();                                                            \
  } while (0)

  for (int base = 0; base < NT; base += 4) {
    G1_ITER(0, base);
    G1_ITER(1, base);
    G1_ITER(2, base);
    G1_ITER(3, base);
  }
#undef G1_ITER

  // ---- epilogue: silu(g)*u -> bf16 act ----
#pragma unroll
  for (int mr = 0; mr < 2; ++mr) {
#pragma unroll
    for (int r = 0; r < 4; ++r) {
      int m = wm * 32 + mr * 16 + (lane >> 4) * 4 + r;
      if (m < rows) {
#pragma unroll
        for (int nr = 0; nr < 2; ++nr) {
          float g = accg[mr][nr][r];
          float u = accu[mr][nr][r];
          float sg = 1.0f / (1.0f + __expf(-g));
          act[(size_t)(row0 + m) * I_ + i0 + wn * 32 + nr * 16 + lr] = f2bf(g * sg * u);
        }
      }
    }
  }
}

// ---------------------------------------------------------------------------
// Kernel 3: grouped GEMM  out[tok,h] += w * (act[slot,:] @ Wd[e]); split-K x2
// Same depth-2 counted-vmcnt pipeline.
// ---------------------------------------------------------------------------
__global__ __launch_bounds__(512, 4) void k_gemm2(
    const short* __restrict__ act, const float* __restrict__ wd,
    const int* __restrict__ offs, const int* __restrict__ slot_tok,
    const float* __restrict__ slot_w, float* __restrict__ out) {
  int e = blockIdx.y >> 4;
  int chunk = blockIdx.y & (CHUNKS_PER_E - 1);
  int lo = offs[e], hi = offs[e + 1];
  int row0 = lo + chunk * BM;
  if (row0 >= hi) return;
  int rows = min(BM, hi - row0);
  int h0 = blockIdx.x * BN;
  int kbase = blockIdx.z * (I_ / SPLITK2);

  __shared__ short sA[4][BM * BK];   // ring-4
  __shared__ short sB[2][BN * BK];   // ring-2, swizzled [n][k]

  int tid = threadIdx.x;
  int lane = tid & 63;
  int w = tid >> 6;
  int wm = w >> 1, wn = w & 1;
  int lr = lane & 15;
  int lk = (lane >> 4) * 8;

  const float* wdE = wd + (size_t)e * I_ * H_;

  int ra = min(16 * w + (lane >> 2), rows - 1);
  const short* srcA = act + (size_t)(row0 + ra) * I_ + kbase + (lane & 3) * 8;
  int up = tid >> 5;                   // k-pair 0..15
  int n2 = (tid & 31) * 2;
  const float* srcB = wdE + (size_t)(kbase + 2 * up) * H_ + h0 + n2;

  f32x4 acc[2][2];
#pragma unroll
  for (int mr = 0; mr < 2; ++mr)
#pragma unroll
    for (int nr = 0; nr < 2; ++nr)
      acc[mr][nr] = (f32x4){0.f, 0.f, 0.f, 0.f};

  float2 bs[2][2];

  // prologue
  gll16(srcA, &sA[0][w * 512]);
  bs[0][0] = *(const float2*)srcB;
  bs[0][1] = *(const float2*)(srcB + H_);
  gll16(srcA + BK, &sA[1][w * 512]);
  bs[1][0] = *(const float2*)(srcB + (size_t)BK * H_);
  bs[1][1] = *(const float2*)(srcB + (size_t)(BK + 1) * H_);
  *(unsigned*)((char*)&sB[0][0] + bswz(n2, 4 * up))     = cvtpk(bs[0][0].x, bs[0][1].x);
  *(unsigned*)((char*)&sB[0][0] + bswz(n2 + 1, 4 * up)) = cvtpk(bs[0][0].y, bs[0][1].y);
  drain_barrier();

  const int NT = (I_ / SPLITK2) / BK;   // 32

#define G2_ITER(U, base_) do {                                                 \
    int t_ = (base_) + (U);                                                    \
    if (t_ + 2 < NT) {                                                         \
      int k2 = (t_ + 2) * BK;                                                  \
      gll16(srcA + k2, &sA[((U) + 2) & 3][w * 512]);                           \
      bs[(U) & 1][0] = *(const float2*)(srcB + (size_t)k2 * H_);               \
      bs[(U) & 1][1] = *(const float2*)(srcB + (size_t)(k2 + 1) * H_);         \
    }                                                                          \
    bf16x8 a0 = *(const bf16x8*)&sA[(U)][(wm * 32 + lr) * BK + lk];            \
    bf16x8 a1 = *(const bf16x8*)&sA[(U)][(wm * 32 + 16 + lr) * BK + lk];       \
    bf16x8 b0 = *(const bf16x8*)((const char*)&sB[(U) & 1][0]                  \
                                 + bswz(wn * 32 + lr, lk * 2));                \
    bf16x8 b1 = *(const bf16x8*)((const char*)&sB[(U) & 1][0]                  \
                                 + bswz(wn * 32 + 16 + lr, lk * 2));           \
    acc[0][0] = MFMA_BF16(a0, b0, acc[0][0], 0, 0, 0);                         \
    acc[0][1] = MFMA_BF16(a0, b1, acc[0][1], 0, 0, 0);                         \
    acc[1][0] = MFMA_BF16(a1, b0, acc[1][0], 0, 0, 0);                         \
    acc[1][1] = MFMA_BF16(a1, b1, acc[1][1], 0, 0, 0);                         \
    if (t_ + 1 < NT) {                                                         \
      *(unsigned*)((char*)&sB[((U) + 1) & 1][0] + bswz(n2, 4 * up))            \
          = cvtpk(bs[((U) + 1) & 1][0].x, bs[((U) + 1) & 1][1].x);             \
      *(unsigned*)((char*)&sB[((U) + 1) & 1][0] + bswz(n2 + 1, 4 * up))        \
          = cvtpk(bs[((U) + 1) & 1][0].y, bs[((U) + 1) & 1][1].y);             \
    }                                                                          \
    pipe_barrier();                                                            \
  } while (0)

  for (int base = 0; base < NT; base += 4) {
    G2_ITER(0, base);
    G2_ITER(1, base);
    G2_ITER(2, base);
    G2_ITER(3, base);
  }
#undef G2_ITER

  // epilogue: scale by combine weight, scatter-add
#pragma unroll
  for (int mr = 0; mr < 2; ++mr) {
#pragma unroll
    for (int r = 0; r < 4; ++r) {
      int m = wm * 32 + mr * 16 + (lane >> 4) * 4 + r;
      if (m < rows) {
        int gs = row0 + m;
        float wc = slot_w[gs];
        int tok = slot_tok[gs];
#pragma unroll
        for (int nr = 0; nr < 2; ++nr)
          atomicAdd(&out[(size_t)tok * H_ + h0 + wn * 32 + nr * 16 + lr],
                    acc[mr][nr][r] * wc);
      }
    }
  }
}

// ---------------------------------------------------------------------------
extern "C" void kernel_launch(void* const* d_in, const int* in_sizes, int n_in,
                              void* d_out, int out_size, void* d_ws, size_t ws_size,
                              hipStream_t stream) {
  const float* hs   = (const float*)d_in[0];
  const float* aff  = (const float*)d_in[1];
  const int*   eidx = (const int*)d_in[2];
  const float* wg   = (const float*)d_in[3];
  const float* wu   = (const float*)d_in[4];
  const float* wd   = (const float*)d_in[5];
  float* out = (float*)d_out;

  char* ws = (char*)d_ws;
  int*   offs     = (int*)ws;                            // 64B reserved
  int*   slot_tok = (int*)(ws + 64);                     // 2048 ints
  float* slot_w   = (float*)(ws + 64 + NSLOT * 4);       // 2048 floats
  short* hs_bf    = (short*)(ws + 64 + NSLOT * 8);       // 2MB bf16 hs
  short* act      = (short*)(ws + 64 + NSLOT * 8 + (size_t)T_ * H_ * 2);  // 8MB

  hipMemsetAsync(d_out, 0, (size_t)out_size * sizeof(float), stream);
  k_build<<<1, T_, 0, stream>>>(aff, eidx, offs, slot_tok, slot_w);
  k_prep<<<(T_ * H_) / (256 * 8), 256, 0, stream>>>(hs, hs_bf);
  k_gemm1<<<dim3(I_ / BN, E_ * CHUNKS_PER_E), 512, 0, stream>>>(hs_bf, wg, wu, offs, slot_tok, act);
  k_gemm2<<<dim3(H_ / BN, E_ * CHUNKS_PER_E, SPLITK2), 512, 0, stream>>>(act, wd, offs, slot_tok, slot_w, out);
}